// Round 1
// baseline (1207.281 us; speedup 1.0000x reference)
//
#include <hip/hip_runtime.h>

// Problem dims
// N=64, CIN=COUT=64, T=256, V=25, S=3, REL=8
// ws layout (float units):
//   [0, 102400)                     : xm[n][c][v]
//   [102400, 102400+3*64*64*700)    : R[s][n][o][u][28] (v padded 25->28)
//   next 128 floats                 : BN sum[64], sumsq[64]

#define WS_XM_F   0
#define WS_R_F    102400
#define WS_R_CNT  (3*64*64*700)
#define WS_BN_F   (WS_R_F + WS_R_CNT)

// ---------------- K1: xm = mean over T ----------------
__global__ __launch_bounds__(256) void k_xm(const float* __restrict__ x,
                                            float* __restrict__ ws) {
    int idx = blockIdx.x * 256 + threadIdx.x;    // 102400 = 64*64*25
    int n = idx / 1600;
    int cv = idx % 1600;
    int c = cv / 25, v = cv % 25;
    const float* xp = x + (n * 64 + c) * 6400 + v;
    float s = 0.f;
    #pragma unroll 8
    for (int t = 0; t < 256; t++) s += xp[t * 25];
    ws[idx] = s * (1.f / 256.f);
}

// ---------------- K2: build R[s][n][o][u][v] ----------------
// one block per (s,n); 256 threads; 60000 B LDS
__global__ __launch_bounds__(256) void k_small(
    const float* __restrict__ ws, float* __restrict__ wsR,
    const float* __restrict__ A, const float* __restrict__ alphap,
    const float* __restrict__ w1, const float* __restrict__ b1,
    const float* __restrict__ w2, const float* __restrict__ b2,
    const float* __restrict__ w4, const float* __restrict__ b4,
    const float* __restrict__ pw1, const float* __restrict__ pb1,
    const float* __restrict__ pw2, const float* __restrict__ pb2,
    const float* __restrict__ dww, const float* __restrict__ pjw,
    const float* __restrict__ beta, const float* __restrict__ gamma) {
    // sm regions: [0,5000) q1 -> later tanh(pool), [5000,10000) staging -> q_all,
    //             [10000,15000) h -> later conv tmp
    __shared__ float sm[15000];
    const int tid = threadIdx.x;
    const int s = blockIdx.x >> 6;   // 0..2
    const int n = blockIdx.x & 63;   // 0..63
    const float alpha = alphap[0];
    const float gam = gamma[s], bet = beta[s];

    // 1. xm[n] -> sm[5000..6600)
    for (int i = tid; i < 1600; i += 256) sm[5000 + i] = ws[n * 1600 + i];
    __syncthreads();

    // 2. x1 (sm 6600..6800), x2 (sm 6800..7000)
    for (int i = tid; i < 400; i += 256) {
        int half = i / 200, j = i % 200;
        int r = j / 25, k = j % 25;
        const float* w = (half ? w2 : w1) + (s * 8 + r) * 64;
        float acc = (half ? b2 : b1)[s * 8 + r];
        for (int c = 0; c < 64; c++) acc += w[c] * sm[5000 + c * 25 + k];
        sm[6600 + i] = acc;
    }
    __syncthreads();

    // 3. q1[r,u,v] = tanh(x1[r,u]-x2[r,v]); A1 (7000..7200), B1 (7200..7400)
    for (int i = tid; i < 5400; i += 256) {
        if (i < 5000) {
            int r = i / 625, uv = i % 625, u = uv / 25, v = uv % 25;
            sm[i] = tanhf(sm[6600 + r * 25 + u] - sm[6800 + r * 25 + v]);
        } else {
            int i2 = i - 5000;  // 0..400
            int half = i2 / 200, j = i2 % 200;
            int r = j / 25, k = j % 25;
            float acc = 0.f;
            for (int p = 0; p < 8; p++)
                acc += pw1[(s * 8 + r) * 16 + half * 8 + p] * sm[6800 + p * 25 + k];
            sm[7000 + i2] = acc;
        }
    }
    __syncthreads();

    // 4. h[r,u,v] = relu(A1[r,u]+B1[r,v]+pb1[r]) -> [10000,15000)
    for (int i = tid; i < 5000; i += 256) {
        int r = i / 625, uv = i % 625, u = uv / 25, v = uv % 25;
        float t = sm[7000 + r * 25 + u] + sm[7200 + r * 25 + v] + pb1[s * 8 + r];
        sm[10000 + i] = t > 0.f ? t : 0.f;
    }
    __syncthreads();

    // 5. q_all = q1 + gamma*q2 -> [5000,10000)
    for (int i = tid; i < 5000; i += 256) {
        int r = i / 625, uv = i % 625;
        float q2 = pb2[s * 8 + r];
        for (int p = 0; p < 8; p++)
            q2 += pw2[(s * 8 + r) * 8 + p] * sm[10000 + p * 625 + uv];
        sm[5000 + i] = sm[i] + gam * q2;
    }
    __syncthreads();

    // 6. depthwise 3x3 conv on q1 -> tmp [10000,15000)
    for (int i = tid; i < 5000; i += 256) {
        int r = i / 625, uv = i % 625, u = uv / 25, v = uv % 25;
        float acc = 0.f;
        for (int di = 0; di < 3; di++) {
            int uu = u + di - 1;
            if (uu < 0 || uu > 24) continue;
            for (int dj = 0; dj < 3; dj++) {
                int vv = v + dj - 1;
                if (vv < 0 || vv > 24) continue;
                acc += sm[r * 625 + uu * 25 + vv] * dww[(s * 8 + r) * 9 + di * 3 + dj];
            }
        }
        sm[10000 + i] = acc;
    }
    __syncthreads();

    // 7. avgpool 3x3 (count_include_pad) + tanh -> overwrite q1 region
    for (int i = tid; i < 5000; i += 256) {
        int r = i / 625, uv = i % 625, u = uv / 25, v = uv % 25;
        float acc = 0.f;
        for (int di = 0; di < 3; di++) {
            int uu = u + di - 1;
            if (uu < 0 || uu > 24) continue;
            for (int dj = 0; dj < 3; dj++) {
                int vv = v + dj - 1;
                if (vv < 0 || vv > 24) continue;
                acc += sm[10000 + r * 625 + uu * 25 + vv];
            }
        }
        sm[i] = tanhf(acc * (1.f / 9.f));
    }
    __syncthreads();

    // 8. R[o,u,v] = alpha*(w4@q_all + b4) + A + beta*(pjw@tanhpool)
    for (int i = tid; i < 40000; i += 256) {
        int o = i / 625, uv = i % 625, u = uv / 25, v = uv % 25;
        float mn = b4[s * 64 + o], aux = 0.f;
        for (int r = 0; r < 8; r++) {
            mn  += w4[(s * 64 + o) * 8 + r] * sm[5000 + r * 625 + uv];
            aux += pjw[(s * 64 + o) * 8 + r] * sm[r * 625 + uv];
        }
        wsR[((s * 64 + n) * 64 + o) * 700 + u * 28 + v] =
            mn * alpha + A[s * 625 + uv] + bet * aux;
    }
}

// ---------------- K4: main fused GEMM-ish kernel ----------------
// block = (n, t-tile of 8); thread: tl = tid>>5 (t), og = tid&31 (2 o's each)
__global__ __launch_bounds__(256) void k_main(
    const float* __restrict__ x, const float* __restrict__ w3,
    const float* __restrict__ b3, const float* __restrict__ wsR,
    float* __restrict__ out) {
    __shared__ float xt[200 * 68];   // [tv][c], pad 64->68 (54.4 KB)
    const int tid = threadIdx.x;
    const int n  = blockIdx.x >> 5;   // 0..63
    const int tb = blockIdx.x & 31;   // 0..31
    const int t0 = tb * 8;
    const int tl = tid >> 5;          // 0..7
    const int og = tid & 31;          // 0..31

    // stage x[n, :, t0:t0+8, :] into LDS (s-independent: once)
    for (int it = tid; it < 3200; it += 256) {   // 16 c-quads x 200 tv
        int cq = it / 200, tv = it % 200;
        const float* xp = x + (n * 64 + cq * 4) * 6400 + t0 * 25 + tv;
        float4 w;
        w.x = xp[0]; w.y = xp[6400]; w.z = xp[12800]; w.w = xp[19200];
        *(float4*)&xt[tv * 68 + cq * 4] = w;
    }
    __syncthreads();

    float yacc[2][25];
    #pragma unroll
    for (int j = 0; j < 2; j++)
        #pragma unroll
        for (int u = 0; u < 25; u++) yacc[j][u] = 0.f;

    for (int s = 0; s < 3; s++) {
        // stage 1: X3[o, tl, v] = b3 + sum_c w3[o,c] * x[c, tl, v]
        float acc1[2][25];
        float bb0 = b3[s * 64 + og * 2], bb1 = b3[s * 64 + og * 2 + 1];
        #pragma unroll
        for (int v = 0; v < 25; v++) { acc1[0][v] = bb0; acc1[1][v] = bb1; }
        const float* w3a = w3 + (s * 64 + og * 2) * 64;
        const float* w3b = w3a + 64;
        for (int cq = 0; cq < 64; cq += 4) {
            float4 wa = *(const float4*)(w3a + cq);
            float4 wb = *(const float4*)(w3b + cq);
            #pragma unroll
            for (int v = 0; v < 25; v++) {
                float4 xv = *(const float4*)&xt[(tl * 25 + v) * 68 + cq];
                acc1[0][v] += wa.x * xv.x + wa.y * xv.y + wa.z * xv.z + wa.w * xv.w;
                acc1[1][v] += wb.x * xv.x + wb.y * xv.y + wb.z * xv.z + wb.w * xv.w;
            }
        }
        // stage 2: y[o, tl, u] += sum_v R[o,u,v] * X3[o, tl, v]
        const float* Rb = wsR + ((s * 64 + n) * 64 + og * 2) * 700;
        #pragma unroll
        for (int j = 0; j < 2; j++) {
            const float* Ro = Rb + j * 700;
            #pragma unroll
            for (int u = 0; u < 25; u++) {
                const float* rr = Ro + u * 28;
                float a = rr[24] * acc1[j][24];
                #pragma unroll
                for (int vq = 0; vq < 24; vq += 4) {
                    float4 r4 = *(const float4*)(rr + vq);
                    a += r4.x * acc1[j][vq] + r4.y * acc1[j][vq + 1] +
                         r4.z * acc1[j][vq + 2] + r4.w * acc1[j][vq + 3];
                }
                yacc[j][u] += a;
            }
        }
    }
    #pragma unroll
    for (int j = 0; j < 2; j++) {
        float* op = out + ((n * 64 + og * 2 + j) * 256 + t0 + tl) * 25;
        #pragma unroll
        for (int u = 0; u < 25; u++) op[u] = yacc[j][u];
    }
}

// ---------------- K5: BN batch stats (sum, sumsq per channel) ----------------
__global__ __launch_bounds__(256) void k_bnstat(const float* __restrict__ y,
                                                float* __restrict__ bnacc) {
    const int tid = threadIdx.x;
    const int o = blockIdx.x >> 3;
    const int ch = blockIdx.x & 7;
    float s = 0.f, s2 = 0.f;
    for (int nn = 0; nn < 8; nn++) {
        const int n = ch * 8 + nn;
        const float4* p = (const float4*)(y + (n * 64 + o) * 6400);
        for (int i = tid; i < 1600; i += 256) {
            float4 v = p[i];
            s  += v.x + v.y + v.z + v.w;
            s2 += v.x * v.x + v.y * v.y + v.z * v.z + v.w * v.w;
        }
    }
    for (int off = 32; off > 0; off >>= 1) {
        s  += __shfl_down(s, off);
        s2 += __shfl_down(s2, off);
    }
    __shared__ float ls[4], ls2[4];
    int wid = tid >> 6;
    if ((tid & 63) == 0) { ls[wid] = s; ls2[wid] = s2; }
    __syncthreads();
    if (tid == 0) {
        atomicAdd(bnacc + o,      ls[0] + ls[1] + ls[2] + ls[3]);
        atomicAdd(bnacc + 64 + o, ls2[0] + ls2[1] + ls2[2] + ls2[3]);
    }
}

// ---------------- K6: normalize + residual + relu ----------------
__global__ __launch_bounds__(256) void k_final(
    float* __restrict__ out, const float* __restrict__ x,
    const float* __restrict__ bnacc,
    const float* __restrict__ bnw, const float* __restrict__ bnb) {
    const int idx4 = blockIdx.x * 256 + threadIdx.x;   // < 6,553,600
    const int o = (idx4 / 1600) & 63;
    const float cnt = 1.f / 409600.f;
    float mean = bnacc[o] * cnt;
    float var = bnacc[64 + o] * cnt - mean * mean;
    float inv = rsqrtf(var + 1e-5f);
    float sc = bnw[o] * inv;
    float sh = bnb[o] - mean * sc;
    float4 y = ((const float4*)out)[idx4];
    float4 xv = ((const float4*)x)[idx4];
    y.x = fmaxf(y.x * sc + sh + xv.x, 0.f);
    y.y = fmaxf(y.y * sc + sh + xv.y, 0.f);
    y.z = fmaxf(y.z * sc + sh + xv.z, 0.f);
    y.w = fmaxf(y.w * sc + sh + xv.w, 0.f);
    ((float4*)out)[idx4] = y;
}

extern "C" void kernel_launch(void* const* d_in, const int* in_sizes, int n_in,
                              void* d_out, int out_size, void* d_ws, size_t ws_size,
                              hipStream_t stream) {
    const float* x     = (const float*)d_in[0];
    const float* A     = (const float*)d_in[1];
    const float* alpha = (const float*)d_in[2];
    const float* w1    = (const float*)d_in[3];
    const float* b1    = (const float*)d_in[4];
    const float* w2    = (const float*)d_in[5];
    const float* b2    = (const float*)d_in[6];
    const float* w3    = (const float*)d_in[7];
    const float* b3    = (const float*)d_in[8];
    const float* w4    = (const float*)d_in[9];
    const float* b4    = (const float*)d_in[10];
    const float* pw1   = (const float*)d_in[11];
    const float* pb1   = (const float*)d_in[12];
    const float* pw2   = (const float*)d_in[13];
    const float* pb2   = (const float*)d_in[14];
    const float* dww   = (const float*)d_in[15];
    const float* pjw   = (const float*)d_in[16];
    const float* beta  = (const float*)d_in[17];
    const float* gamma = (const float*)d_in[18];
    const float* bnw   = (const float*)d_in[19];
    const float* bnb   = (const float*)d_in[20];
    float* out = (float*)d_out;
    float* ws  = (float*)d_ws;
    float* wsR  = ws + WS_R_F;
    float* wsBN = ws + WS_BN_F;

    k_xm<<<400, 256, 0, stream>>>(x, ws);
    k_small<<<192, 256, 0, stream>>>(ws, wsR, A, alpha, w1, b1, w2, b2,
                                     w4, b4, pw1, pb1, pw2, pb2, dww, pjw,
                                     beta, gamma);
    hipMemsetAsync(wsBN, 0, 128 * sizeof(float), stream);
    k_main<<<2048, 256, 0, stream>>>(x, w3, b3, wsR, out);
    k_bnstat<<<512, 256, 0, stream>>>(out, wsBN);
    k_final<<<25600, 256, 0, stream>>>(out, x, wsBN, bnw, bnb);
}

// Round 6
// 530.636 us; speedup vs baseline: 2.2752x; 2.2752x over previous
//
#include <hip/hip_runtime.h>

// N=64, CIN=COUT=64, T=256, V=25, S=3, REL=8
// ws layout (bytes):
//   [0, 409600)              : xm[n][c][v] fp32 (102400 floats)
//   [409600, +17301504)      : R_bf16[s][n][o][704]  (o-row = v*28+u, u pad 25..27 = 0, els 700..703 unused)
//   [17711104, +512)         : BN sum[64], sumsq[64] fp32

#define WS_R_BYTE   409600
#define WS_BN_BYTE  17711104

typedef __attribute__((ext_vector_type(8))) short bf16x8;
typedef __attribute__((ext_vector_type(4))) float f32x4;

static __device__ __forceinline__ unsigned short f2bf(float f) {
    unsigned int u = __float_as_uint(f);
    u += 0x7fff + ((u >> 16) & 1);          // RNE (finite values)
    return (unsigned short)(u >> 16);
}
static __device__ __forceinline__ float bf2f(unsigned short s) {
    return __uint_as_float(((unsigned int)s) << 16);
}

// ---------------- K1: xm = mean over T ----------------
__global__ __launch_bounds__(256) void k_xm(const float* __restrict__ x,
                                            float* __restrict__ ws) {
    int idx = blockIdx.x * 256 + threadIdx.x;    // 102400 = 64*64*25
    int n = idx / 1600;
    int cv = idx % 1600;
    int c = cv / 25, v = cv % 25;
    const float* xp = x + (n * 64 + c) * 6400 + v;
    float s = 0.f;
    #pragma unroll 8
    for (int t = 0; t < 256; t++) s += xp[t * 25];
    ws[idx] = s * (1.f / 256.f);
}

// ---------------- K2: build R_bf16[s][n][o][v][u28] ----------------
// one block per (s,n); 512 threads; 60000 B LDS
__global__ __launch_bounds__(512) void k_small(
    const float* __restrict__ ws, unsigned short* __restrict__ Rg,
    const float* __restrict__ A, const float* __restrict__ alphap,
    const float* __restrict__ w1, const float* __restrict__ b1,
    const float* __restrict__ w2, const float* __restrict__ b2,
    const float* __restrict__ w4, const float* __restrict__ b4,
    const float* __restrict__ pw1, const float* __restrict__ pb1,
    const float* __restrict__ pw2, const float* __restrict__ pb2,
    const float* __restrict__ dww, const float* __restrict__ pjw,
    const float* __restrict__ beta, const float* __restrict__ gamma) {
    __shared__ float sm[15000];
    const int tid = threadIdx.x;
    const int s = blockIdx.x >> 6;   // 0..2
    const int n = blockIdx.x & 63;   // 0..63
    const float alpha = alphap[0];
    const float gam = gamma[s], bet = beta[s];

    // 1. xm[n] -> sm[5000..6600)
    for (int i = tid; i < 1600; i += 512) sm[5000 + i] = ws[n * 1600 + i];
    __syncthreads();

    // 2. x1 (sm 6600..6800), x2 (sm 6800..7000)
    for (int i = tid; i < 400; i += 512) {
        int half = i / 200, j = i % 200;
        int r = j / 25, k = j % 25;
        const float* w = (half ? w2 : w1) + (s * 8 + r) * 64;
        float acc = (half ? b2 : b1)[s * 8 + r];
        for (int c = 0; c < 64; c++) acc += w[c] * sm[5000 + c * 25 + k];
        sm[6600 + i] = acc;
    }
    __syncthreads();

    // 3. q1[r,u,v] = tanh(x1[r,u]-x2[r,v]); A1 (7000..7200), B1 (7200..7400)
    for (int i = tid; i < 5400; i += 512) {
        if (i < 5000) {
            int r = i / 625, uv = i % 625, u = uv / 25, v = uv % 25;
            sm[i] = tanhf(sm[6600 + r * 25 + u] - sm[6800 + r * 25 + v]);
        } else {
            int i2 = i - 5000;  // 0..400
            int half = i2 / 200, j = i2 % 200;
            int r = j / 25, k = j % 25;
            float acc = 0.f;
            for (int p = 0; p < 8; p++)
                acc += pw1[(s * 8 + r) * 16 + half * 8 + p] * sm[6800 + p * 25 + k];
            sm[7000 + i2] = acc;
        }
    }
    __syncthreads();

    // 4. h[r,u,v] = relu(A1[r,u]+B1[r,v]+pb1[r]) -> [10000,15000)
    for (int i = tid; i < 5000; i += 512) {
        int r = i / 625, uv = i % 625, u = uv / 25, v = uv % 25;
        float t = sm[7000 + r * 25 + u] + sm[7200 + r * 25 + v] + pb1[s * 8 + r];
        sm[10000 + i] = t > 0.f ? t : 0.f;
    }
    __syncthreads();

    // 5. q_all = q1 + gamma*q2 -> [5000,10000)
    for (int i = tid; i < 5000; i += 512) {
        int r = i / 625, uv = i % 625;
        float q2 = pb2[s * 8 + r];
        for (int p = 0; p < 8; p++)
            q2 += pw2[(s * 8 + r) * 8 + p] * sm[10000 + p * 625 + uv];
        sm[5000 + i] = sm[i] + gam * q2;
    }
    __syncthreads();

    // 6. depthwise 3x3 conv on q1 -> tmp [10000,15000)
    for (int i = tid; i < 5000; i += 512) {
        int r = i / 625, uv = i % 625, u = uv / 25, v = uv % 25;
        float acc = 0.f;
        for (int di = 0; di < 3; di++) {
            int uu = u + di - 1;
            if (uu < 0 || uu > 24) continue;
            for (int dj = 0; dj < 3; dj++) {
                int vv = v + dj - 1;
                if (vv < 0 || vv > 24) continue;
                acc += sm[r * 625 + uu * 25 + vv] * dww[(s * 8 + r) * 9 + di * 3 + dj];
            }
        }
        sm[10000 + i] = acc;
    }
    __syncthreads();

    // 7. avgpool 3x3 (count_include_pad) + tanh -> overwrite q1 region
    for (int i = tid; i < 5000; i += 512) {
        int r = i / 625, uv = i % 625, u = uv / 25, v = uv % 25;
        float acc = 0.f;
        for (int di = 0; di < 3; di++) {
            int uu = u + di - 1;
            if (uu < 0 || uu > 24) continue;
            for (int dj = 0; dj < 3; dj++) {
                int vv = v + dj - 1;
                if (vv < 0 || vv > 24) continue;
                acc += sm[10000 + r * 625 + uu * 25 + vv];
            }
        }
        sm[i] = tanhf(acc * (1.f / 9.f));
    }
    __syncthreads();

    // 8. R[o][v][u] = alpha*(w4@q_all + b4) + A + beta*(pjw@tanhpool), store bf16
    unsigned short* Rb = Rg + (unsigned)((s * 64 + n) * 64) * 704;
    for (int i = tid; i < 40000; i += 512) {
        int o = i / 625, vu = i % 625, vv = vu / 25, uu = vu % 25;
        int quv = uu * 25 + vv;     // [u][v] index into q_all / pool
        float mn = b4[s * 64 + o], aux = 0.f;
        for (int r = 0; r < 8; r++) {
            mn  += w4[(s * 64 + o) * 8 + r] * sm[5000 + r * 625 + quv];
            aux += pjw[(s * 64 + o) * 8 + r] * sm[r * 625 + quv];
        }
        Rb[o * 704 + vv * 28 + uu] = f2bf(mn * alpha + A[s * 625 + quv] + bet * aux);
    }
    // zero u-pad (u = 25..27)
    for (int i = tid; i < 64 * 25 * 3; i += 512) {
        int o = i / 75, rem = i % 75, vv = rem / 3, uu = 25 + rem % 3;
        Rb[o * 704 + vv * 28 + uu] = 0;
    }
}

// ---------------- K3: main fused kernel: MFMA stage-1 + VALU stage-2 ----------------
// block = (n, t-tile of 16); 256 threads = 4 waves; wave w = o-chunk [w*16, w*16+16)
// LDS: xb 51200 B (bf16 x-tile [tv400][c64], XOR-swizzled 16B chunks) + Rs 10752 B
__global__ __launch_bounds__(256, 2) void k_main(
    const float* __restrict__ x, const float* __restrict__ w3,
    const float* __restrict__ b3, const unsigned short* __restrict__ Rg,
    float* __restrict__ out) {
    __shared__ __align__(16) unsigned short xb[400 * 64];   // 51200 B
    __shared__ __align__(16) unsigned short Rs[64 * 84];    // 10752 B
    const int tid  = threadIdx.x;
    const int n    = blockIdx.x >> 4;
    const int t0   = (blockIdx.x & 15) * 16;
    const int lane = tid & 63;
    const int w    = tid >> 6;          // wave id = o-chunk
    const int ln15 = lane & 15;
    const int q    = lane >> 4;         // quad
    const int og   = w * 16 + ln15;     // this lane's o

    // ---- stage x[n, :, t0:t0+16, :] -> xb bf16, swizzled ----
    {
        const float* xbase = x + n * 409600 + t0 * 25;
        #pragma unroll 5
        for (int k = 0; k < 25; k++) {
            int i  = tid + k * 256;      // 0..6399
            int tv = i % 400;
            int cq = i / 400;            // c-quad 0..15
            const float* p = xbase + cq * 4 * 6400 + tv;
            ushort4 h;
            h.x = f2bf(p[0]); h.y = f2bf(p[6400]); h.z = f2bf(p[12800]); h.w = f2bf(p[19200]);
            int addr = tv * 64 + (((cq >> 1) ^ (tv & 7)) << 3) + ((cq & 1) << 2);
            *(ushort4*)&xb[addr] = h;
        }
    }

    float yacc[26][4];
    #pragma unroll
    for (int u = 0; u < 26; u++)
        #pragma unroll
        for (int r = 0; r < 4; r++) yacc[u][r] = 0.f;

    for (int s = 0; s < 3; s++) {
        // B-frags (w3^T) + bias for this (s, og): hoisted out of v-loop
        bf16x8 bfr[2];
        {
            const float* wp = w3 + (s * 64 + og) * 64;
            #pragma unroll
            for (int ks = 0; ks < 2; ks++)
                #pragma unroll
                for (int j = 0; j < 8; j++)
                    bfr[ks][j] = (short)f2bf(wp[ks * 32 + q * 8 + j]);
        }
        const float bias = b3[s * 64 + og];
        const unsigned short* Rsrc = Rg + (unsigned)((s * 64 + n) * 64) * 704;

        for (int vg = 0; vg < 9; vg++) {
            const int nv = (vg < 8) ? 3 : 1;
            __syncthreads();    // previous Rs consumers done
            // stage R[s][all o][v in vg][u28] -> Rs[o][iv*28+u]
            {
                const int cpo = 7 * nv;            // ushort4 chunks per o
                const int nchunks = 64 * cpo;
                for (int i = tid; i < nchunks; i += 256) {
                    int o = i / cpo, ch = i % cpo;
                    *(ushort4*)&Rs[o * 84 + ch * 4] =
                        *(const ushort4*)&Rsrc[o * 704 + vg * 84 + ch * 4];
                }
            }
            __syncthreads();

            // stage 1: X3 C-frags for the nv v's of this group (MFMA)
            f32x4 c[3];
            #pragma unroll
            for (int iv = 0; iv < 3; iv++) {
                if (iv >= nv) break;
                const int v   = vg * 3 + iv;
                const int row = ln15 * 25 + v;
                const int sw  = row & 7;
                bf16x8 a0 = *(const bf16x8*)&xb[row * 64 + ((q ^ sw) << 3)];
                bf16x8 a1 = *(const bf16x8*)&xb[row * 64 + (((4 + q) ^ sw) << 3)];
                f32x4 cc; cc[0] = bias; cc[1] = bias; cc[2] = bias; cc[3] = bias;
                cc = __builtin_amdgcn_mfma_f32_16x16x32_bf16(a0, bfr[0], cc, 0, 0, 0);
                cc = __builtin_amdgcn_mfma_f32_16x16x32_bf16(a1, bfr[1], cc, 0, 0, 0);
                c[iv] = cc;
            }
            // stage 2: y[u][t-reg] += R[og][v][u] * X3 (fp32 VALU on C-frags)
            #pragma unroll
            for (int iv = 0; iv < 3; iv++) {
                if (iv >= nv) break;
                const unsigned short* rr = &Rs[og * 84 + iv * 28];
                f32x4 cc = c[iv];
                #pragma unroll
                for (int ug = 0; ug < 6; ug++) {
                    ushort4 r4 = *(const ushort4*)(rr + ug * 4);
                    float f0 = bf2f(r4.x), f1 = bf2f(r4.y);
                    float f2 = bf2f(r4.z), f3 = bf2f(r4.w);
                    #pragma unroll
                    for (int r = 0; r < 4; r++) {
                        yacc[ug * 4 + 0][r] += f0 * cc[r];
                        yacc[ug * 4 + 1][r] += f1 * cc[r];
                        yacc[ug * 4 + 2][r] += f2 * cc[r];
                        yacc[ug * 4 + 3][r] += f3 * cc[r];
                    }
                }
                float f24 = bf2f(rr[24]);
                #pragma unroll
                for (int r = 0; r < 4; r++) yacc[24][r] += f24 * cc[r];
            }
        }
    }

    // store y[n][og][t0 + q*4 + r][u]
    float* op = out + (n * 64 + og) * 6400 + t0 * 25;
    #pragma unroll
    for (int r = 0; r < 4; r++) {
        float* opr = op + (q * 4 + r) * 25;
        #pragma unroll
        for (int u = 0; u < 25; u++) opr[u] = yacc[u][r];
    }
}

// ---------------- K4: BN batch stats (sum, sumsq per channel) ----------------
__global__ __launch_bounds__(256) void k_bnstat(const float* __restrict__ y,
                                                float* __restrict__ bnacc) {
    const int tid = threadIdx.x;
    const int o = blockIdx.x >> 3;
    const int ch = blockIdx.x & 7;
    float s = 0.f, s2 = 0.f;
    for (int nn = 0; nn < 8; nn++) {
        const int n = ch * 8 + nn;
        const float4* p = (const float4*)(y + (n * 64 + o) * 6400);
        for (int i = tid; i < 1600; i += 256) {
            float4 v = p[i];
            s  += v.x + v.y + v.z + v.w;
            s2 += v.x * v.x + v.y * v.y + v.z * v.z + v.w * v.w;
        }
    }
    for (int off = 32; off > 0; off >>= 1) {
        s  += __shfl_down(s, off);
        s2 += __shfl_down(s2, off);
    }
    __shared__ float ls[4], ls2[4];
    int wid = tid >> 6;
    if ((tid & 63) == 0) { ls[wid] = s; ls2[wid] = s2; }
    __syncthreads();
    if (tid == 0) {
        atomicAdd(bnacc + o,      ls[0] + ls[1] + ls[2] + ls[3]);
        atomicAdd(bnacc + 64 + o, ls2[0] + ls2[1] + ls2[2] + ls2[3]);
    }
}

// ---------------- K5: normalize + residual + relu ----------------
// out_size = 26,214,400 floats = 6,553,600 float4 -> 25600 blocks x 256 threads
__global__ __launch_bounds__(256) void k_final(
    float* __restrict__ out, const float* __restrict__ x,
    const float* __restrict__ bnacc,
    const float* __restrict__ bnw, const float* __restrict__ bnb) {
    const int idx4 = blockIdx.x * 256 + threadIdx.x;   // < 6,553,600
    const int o = (idx4 / 1600) & 63;
    const float cnt = 1.f / 409600.f;
    float mean = bnacc[o] * cnt;
    float var = bnacc[64 + o] * cnt - mean * mean;
    float inv = rsqrtf(var + 1e-5f);
    float sc = bnw[o] * inv;
    float sh = bnb[o] - mean * sc;
    float4 y = ((const float4*)out)[idx4];
    float4 xv = ((const float4*)x)[idx4];
    y.x = fmaxf(y.x * sc + sh + xv.x, 0.f);
    y.y = fmaxf(y.y * sc + sh + xv.y, 0.f);
    y.z = fmaxf(y.z * sc + sh + xv.z, 0.f);
    y.w = fmaxf(y.w * sc + sh + xv.w, 0.f);
    ((float4*)out)[idx4] = y;
}

extern "C" void kernel_launch(void* const* d_in, const int* in_sizes, int n_in,
                              void* d_out, int out_size, void* d_ws, size_t ws_size,
                              hipStream_t stream) {
    const float* x     = (const float*)d_in[0];
    const float* A     = (const float*)d_in[1];
    const float* alpha = (const float*)d_in[2];
    const float* w1    = (const float*)d_in[3];
    const float* b1    = (const float*)d_in[4];
    const float* w2    = (const float*)d_in[5];
    const float* b2    = (const float*)d_in[6];
    const float* w3    = (const float*)d_in[7];
    const float* b3    = (const float*)d_in[8];
    const float* w4    = (const float*)d_in[9];
    const float* b4    = (const float*)d_in[10];
    const float* pw1   = (const float*)d_in[11];
    const float* pb1   = (const float*)d_in[12];
    const float* pw2   = (const float*)d_in[13];
    const float* pb2   = (const float*)d_in[14];
    const float* dww   = (const float*)d_in[15];
    const float* pjw   = (const float*)d_in[16];
    const float* beta  = (const float*)d_in[17];
    const float* gamma = (const float*)d_in[18];
    const float* bnw   = (const float*)d_in[19];
    const float* bnb   = (const float*)d_in[20];
    float* out = (float*)d_out;
    float* ws  = (float*)d_ws;
    unsigned short* wsR = (unsigned short*)((char*)d_ws + WS_R_BYTE);
    float* wsBN = (float*)((char*)d_ws + WS_BN_BYTE);

    k_xm<<<400, 256, 0, stream>>>(x, ws);
    k_small<<<192, 512, 0, stream>>>(ws, wsR, A, alpha, w1, b1, w2, b2,
                                     w4, b4, pw1, pb1, pw2, pb2, dww, pjw,
                                     beta, gamma);
    hipMemsetAsync(wsBN, 0, 128 * sizeof(float), stream);
    k_main<<<1024, 256, 0, stream>>>(x, w3, b3, wsR, out);
    k_bnstat<<<512, 256, 0, stream>>>(out, wsBN);
    k_final<<<25600, 256, 0, stream>>>(out, x, wsBN, bnw, bnb);
}